// Round 1
// baseline (91706.171 us; speedup 1.0000x reference)
//
#include <hip/hip_runtime.h>
#include <stdint.h>

#define L4   250   // chase chunk length
#define GRP  50    // chunks per map-composition group
#define PF   32    // feat prefetch depth in k_chain (covers ~900cy HBM latency)

// DPP row_ror:K — dst lane i reads src lane (i-K)&15 within its row of 16.
// (VALU-speed cross-lane; no LDS path, unlike ds_bpermute.)
template<int K>
__device__ __forceinline__ float rotr(float x) {
  return __int_as_float(__builtin_amdgcn_mov_dpp(__float_as_int(x), 0x120 + K, 0xF, 0xF, false));
}

// One exact Viterbi max-step: m = max_p fl(fv[p] + tr[n][p]).
// Lane layout: n = lane&15, lane holds fv[n]; trr[k] = tr[n][(n-k)&15].
// c_k = fv[(n-k)&15] + tr[n][(n-k)&15]; k=0..15 covers every p exactly once.
// fp32 max is exact & order-independent -> any tree shape is bit-identical
// to the reference's jnp.max. Triples written to encourage v_max3_f32.
__device__ __forceinline__ float vstep(float fv, const float* __restrict__ trr) {
  float c0  = fv           + trr[0];
  float c1  = rotr<1 >(fv) + trr[1];
  float c2  = rotr<2 >(fv) + trr[2];
  float c3  = rotr<3 >(fv) + trr[3];
  float c4  = rotr<4 >(fv) + trr[4];
  float c5  = rotr<5 >(fv) + trr[5];
  float c6  = rotr<6 >(fv) + trr[6];
  float c7  = rotr<7 >(fv) + trr[7];
  float c8  = rotr<8 >(fv) + trr[8];
  float c9  = rotr<9 >(fv) + trr[9];
  float c10 = rotr<10>(fv) + trr[10];
  float c11 = rotr<11>(fv) + trr[11];
  float c12 = rotr<12>(fv) + trr[12];
  float c13 = rotr<13>(fv) + trr[13];
  float c14 = rotr<14>(fv) + trr[14];
  float c15 = rotr<15>(fv) + trr[15];
  float t0 = fmaxf(fmaxf(c0,  c1),  c2);
  float t1 = fmaxf(fmaxf(c3,  c4),  c5);
  float t2 = fmaxf(fmaxf(c6,  c7),  c8);
  float t3 = fmaxf(fmaxf(c9,  c10), c11);
  float t4 = fmaxf(fmaxf(c12, c13), c14);
  float u0 = fmaxf(fmaxf(t0, t1), t2);
  float u1 = fmaxf(fmaxf(t3, t4), c15);
  return fmaxf(u0, u1);
}

// ---------------------------------------------------------------------------
// K1: value-only exact Viterbi forward chain. ONE wave.
// Lane l: n = l&15 (tag); rows (l>>4) are 4x replicas computing identical
// values (row_ror operates within each 16-lane row). No LDS-path ops in the
// recurrence: redistribution is free via DPP row rotations fused into adds.
// Streams FV[t] (fv entering step t) to memory; FV[0] = zeros.
// All 64 lanes store the same replicated 64B (identical values; coalesced).
// Backpointers are NOT computed here (k_bp recomputes them in parallel).
// ---------------------------------------------------------------------------
__global__ __launch_bounds__(64)
void k_chain(const float* __restrict__ feats, const float* __restrict__ trans,
             float* __restrict__ FV, int* __restrict__ last_tag, int T) {
  const int l = threadIdx.x;
  const int n = l & 15;

  // Per-lane rotated transition row: trr[k] = trans[n][(n-k)&15]
  float trr[16];
  #pragma unroll
  for (int k = 0; k < 16; ++k) trr[k] = trans[n * 16 + ((n - k) & 15)];

  if (l < 16) FV[l] = 0.0f; // FV[0] = init_fv = zeros

  float fv = 0.0f;

  float fbuf[PF];
  #pragma unroll
  for (int i = 0; i < PF; ++i) {
    int idx = i < T ? i : (T - 1);
    fbuf[i] = feats[(size_t)idx * 16 + n];
  }

  int t = 0;
  const int Tm = T - (T % PF);
  for (; t < Tm; t += PF) {
    #pragma unroll
    for (int u = 0; u < PF; ++u) {
      const int tt = t + u;
      float m  = vstep(fv, trr);
      float nf = m + fbuf[u];
      // prefetch feat for step tt+PF
      int pfi = tt + PF; if (pfi > T - 1) pfi = T - 1;
      fbuf[u] = feats[(size_t)pfi * 16 + n];
      // stream fv entering step tt+1 (all rows write identical 64B)
      FV[(size_t)(tt + 1) * 16 + n] = nf;
      fv = nf;
    }
  }
  for (; t < T; ++t) { // tail (T % PF steps) — direct loads, negligible
    float m  = vstep(fv, trr);
    float nf = m + feats[(size_t)t * 16 + n];
    FV[(size_t)(t + 1) * 16 + n] = nf;
    fv = nf;
  }

  // last_tag = argmax of final fv (first-index tie-break, ascending p).
  float bv = __shfl(fv, 0, 64); int bi = 0;
  #pragma unroll
  for (int p = 1; p < 16; ++p) {
    float ov = __shfl(fv, p, 64);
    if (ov > bv) { bv = ov; bi = p; }
  }
  if (l == 0) *last_tag = bi;
}

// ---------------------------------------------------------------------------
// K2: parallel backpointer recompute. Thread per t.
// bp[t][n] = argmax_p fl(FV[t][p] + tr[n][p]), strict-> scan (first-max),
// bit-identical to the reference's jnp.argmax(scores, axis=1).
// ---------------------------------------------------------------------------
__global__ __launch_bounds__(256)
void k_bp(const float* __restrict__ FV, const float* __restrict__ trans,
          uint4* __restrict__ bp, int T) {
  __shared__ float str[256];
  const int tid = threadIdx.x;
  str[tid] = trans[tid];
  __syncthreads();
  const int t = blockIdx.x * blockDim.x + tid;
  if (t >= T) return;
  const float4* fr = (const float4*)(FV + (size_t)t * 16);
  float4 q0 = fr[0], q1 = fr[1], q2 = fr[2], q3 = fr[3];
  float fv[16] = {q0.x, q0.y, q0.z, q0.w, q1.x, q1.y, q1.z, q1.w,
                  q2.x, q2.y, q2.z, q2.w, q3.x, q3.y, q3.z, q3.w};
  uint32_t w[4];
  #pragma unroll
  for (int g = 0; g < 4; ++g) {
    uint32_t word = 0;
    #pragma unroll
    for (int s = 0; s < 4; ++s) {
      const int nn = 4 * g + s;
      float best = fv[0] + str[nn * 16 + 0];
      int bi = 0;
      #pragma unroll
      for (int p = 1; p < 16; ++p) {
        float v = fv[p] + str[nn * 16 + p];
        if (v > best) { best = v; bi = p; }
      }
      word |= (uint32_t)bi << (8 * s);
    }
    w[g] = word;
  }
  bp[t] = make_uint4(w[0], w[1], w[2], w[3]);
}

// ---------------------------------------------------------------------------
// K3: per-chunk 16-hypothesis backtrack (exact integer pointer chase).
// ---------------------------------------------------------------------------
__global__ __launch_bounds__(64)
void k_chase(const unsigned char* __restrict__ bp, unsigned char* __restrict__ st,
             unsigned char* __restrict__ maps, int T, int C) {
  const int tid = threadIdx.x;
  const int chunk = blockIdx.x * 4 + (tid >> 4);
  const int h = tid & 15;
  if (chunk >= C) return;
  const int a = chunk * L4;
  int b = a + L4; if (b > T) b = T;
  int cur = h;
  for (int t = b - 1; t >= a; --t) {
    cur = bp[(size_t)t * 16 + cur];
    st[(size_t)t * 16 + h] = (unsigned char)cur;
  }
  maps[chunk * 16 + h] = (unsigned char)cur;
}

// ---------------------------------------------------------------------------
// K4: compose GRP consecutive chunk maps into one super-map per group.
// ---------------------------------------------------------------------------
__global__ __launch_bounds__(64)
void k_group(const unsigned char* __restrict__ maps, unsigned char* __restrict__ sup,
             int C, int NG) {
  const int g = blockIdx.x;
  const int e = threadIdx.x;
  if (g >= NG || e >= 16) return;
  int hi = g * GRP + GRP - 1; if (hi > C - 1) hi = C - 1;
  int cur = e;
  for (int c = hi; c >= g * GRP; --c) cur = maps[c * 16 + cur];
  sup[g * 16 + e] = (unsigned char)cur;
}

// ---------------------------------------------------------------------------
// K5: resolve true tag at every chunk's end boundary.
// ---------------------------------------------------------------------------
__global__ __launch_bounds__(128)
void k_resolve(const unsigned char* __restrict__ maps, const unsigned char* __restrict__ sup,
               const int* __restrict__ last_tag, unsigned char* __restrict__ s_arr,
               int C, int NG) {
  __shared__ unsigned char Sg[4096];
  const int tid = threadIdx.x;
  if (tid == 0) {
    int cur = *last_tag;
    for (int g = NG - 1; g >= 0; --g) {
      Sg[g] = (unsigned char)cur;
      cur = sup[g * 16 + cur];
    }
  }
  __syncthreads();
  for (int g = tid; g < NG; g += blockDim.x) {
    int cur = Sg[g];
    int hi = g * GRP + GRP - 1; if (hi > C - 1) hi = C - 1;
    for (int c = hi; c >= g * GRP; --c) {
      s_arr[c] = (unsigned char)cur;
      cur = maps[c * 16 + cur];
    }
  }
}

// ---------------------------------------------------------------------------
// K6: emit out[t] = st[t*16 + s_arr[t / L4]] as int32.
// ---------------------------------------------------------------------------
__global__ void k_emit(const unsigned char* __restrict__ st,
                       const unsigned char* __restrict__ s_arr,
                       int* __restrict__ out, int T) {
  int t = blockIdx.x * blockDim.x + threadIdx.x;
  if (t < T) out[t] = (int)st[(size_t)t * 16 + s_arr[t / L4]];
}

extern "C" void kernel_launch(void* const* d_in, const int* in_sizes, int n_in,
                              void* d_out, int out_size, void* d_ws, size_t ws_size,
                              hipStream_t stream) {
  const float* feats = (const float*)d_in[0];   // [1, T, 16] fp32
  const float* trans = (const float*)d_in[1];   // [16, 16]  fp32
  int* out = (int*)d_out;                       // [T] int32

  const int T  = in_sizes[0] / 16;
  const int C  = (T + L4 - 1) / L4;
  const int NG = (C + GRP - 1) / GRP;

  char* ws = (char*)d_ws;
  float* FV           = (float*)ws;                          // (T+1)*16 floats
  unsigned char* bp   = (unsigned char*)(FV + (size_t)(T + 1) * 16); // T*16 B, 16B-aligned
  unsigned char* st   = bp + (size_t)T * 16;                 // T*16 B
  unsigned char* maps = st + (size_t)T * 16;                 // C*16
  unsigned char* sup  = maps + (size_t)C * 16;               // NG*16
  unsigned char* sarr = sup + (size_t)NG * 16;               // C
  int* last_tag = (int*)(((uintptr_t)(sarr + C) + 15) & ~(uintptr_t)15);
  size_t need = (size_t)((char*)(last_tag + 1) - ws);
  if (ws_size < need) return;  // insufficient scratch -> fail visibly

  k_chain<<<1, 64, 0, stream>>>(feats, trans, FV, last_tag, T);
  k_bp<<<(T + 255) / 256, 256, 0, stream>>>(FV, trans, (uint4*)bp, T);
  k_chase<<<(C + 3) / 4, 64, 0, stream>>>(bp, st, maps, T, C);
  k_group<<<NG, 64, 0, stream>>>(maps, sup, C, NG);
  k_resolve<<<1, 128, 0, stream>>>(maps, sup, last_tag, sarr, C, NG);
  const int thr = 256;
  k_emit<<<(T + thr - 1) / thr, thr, 0, stream>>>(st, sarr, out, T);
}

// Round 3
// 67356.287 us; speedup vs baseline: 1.3615x; 1.3615x over previous
//
#include <hip/hip_runtime.h>
#include <stdint.h>

#define L4   250   // chase chunk length
#define GRP  50    // chunks per map-composition group
#define PF   32    // feat prefetch depth in k_chain
#define CSZ  256   // checkpoint interval (power of 2)
#define CSB  8     // log2(CSZ)

// DPP row_ror:K — dst lane i reads src lane (i-K)&15 within its row of 16.
// Direction verified bit-exact in prior rounds (absmax 0 with matched trr).
template<int K>
__device__ __forceinline__ float rotr(float x) {
  return __int_as_float(__builtin_amdgcn_mov_dpp(__float_as_int(x), 0x120 + K, 0xF, 0xF, false));
}

// Cross-half (lane l <-> l^32) max, VALU-speed on gfx950 via permlane32_swap.
// Feeding (m,m) and maxing both outputs yields max(m[l], m[l^32]) regardless
// of which output carries which half. Fallback: __shfl_xor (LDS path).
__device__ __forceinline__ float xhalf_max(float m) {
#if __has_builtin(__builtin_amdgcn_permlane32_swap)
  typedef int v2i __attribute__((ext_vector_type(2)));
  v2i r = __builtin_amdgcn_permlane32_swap(__float_as_int(m), __float_as_int(m), false, false);
  return fmaxf(__int_as_float(r[0]), __int_as_float(r[1]));
#else
  return fmaxf(m, __shfl_xor(m, 32, 64));
#endif
}

// Full 16-candidate exact step (used by throughput kernel k_fv).
// Lane layout: n = lane&15, lane holds fv[n]; trr[k] = tr[n][(n-k)&15].
// fp32 max over 16 finite values is order-independent -> bit-identical to
// the reference's jnp.max regardless of tree shape.
__device__ __forceinline__ float vstep(float fv, const float* __restrict__ trr) {
  float c0  = fv           + trr[0];
  float c1  = rotr<1 >(fv) + trr[1];
  float c2  = rotr<2 >(fv) + trr[2];
  float c3  = rotr<3 >(fv) + trr[3];
  float c4  = rotr<4 >(fv) + trr[4];
  float c5  = rotr<5 >(fv) + trr[5];
  float c6  = rotr<6 >(fv) + trr[6];
  float c7  = rotr<7 >(fv) + trr[7];
  float c8  = rotr<8 >(fv) + trr[8];
  float c9  = rotr<9 >(fv) + trr[9];
  float c10 = rotr<10>(fv) + trr[10];
  float c11 = rotr<11>(fv) + trr[11];
  float c12 = rotr<12>(fv) + trr[12];
  float c13 = rotr<13>(fv) + trr[13];
  float c14 = rotr<14>(fv) + trr[14];
  float c15 = rotr<15>(fv) + trr[15];
  float t0 = fmaxf(fmaxf(c0,  c1),  c2);
  float t1 = fmaxf(fmaxf(c3,  c4),  c5);
  float t2 = fmaxf(fmaxf(c6,  c7),  c8);
  float t3 = fmaxf(fmaxf(c9,  c10), c11);
  float t4 = fmaxf(fmaxf(c12, c13), c14);
  float u0 = fmaxf(fmaxf(t0, t1), t2);
  float u1 = fmaxf(fmaxf(t3, t4), c15);
  return fmaxf(u0, u1);
}

// Split 8-candidate exact step (serial chain). Invariant: lane (h,n) holds
// fvh = fv[nid], nid = n ^ (8h) = (n+8h) mod 16. Uniform rotr<i>(fvh) at lane
// (h,n) gives fv[(nid-i)&15]; trr[i] = tr[n][(nid-i)&15]; union over h,i =
// all 16 p, each exactly once. Cross-half merge gives the full max M for tag
// n in all lanes (bit-exact: float max is order-independent; candidate adds
// identical to reference). Next-state: lane must hold nf[nid]; Mr = rotr<8>(M)
// supplies M[n^8] for the upper half; fb is loaded at index nid.
__device__ __forceinline__ float step8(float fvh, const float* __restrict__ trr,
                                       bool hi, float fb) {
  float c0 = fvh          + trr[0];
  float c1 = rotr<1>(fvh) + trr[1];
  float c2 = rotr<2>(fvh) + trr[2];
  float c3 = rotr<3>(fvh) + trr[3];
  float c4 = rotr<4>(fvh) + trr[4];
  float c5 = rotr<5>(fvh) + trr[5];
  float c6 = rotr<6>(fvh) + trr[6];
  float c7 = rotr<7>(fvh) + trr[7];
  float t0 = fmaxf(fmaxf(c0, c1), c2);
  float t1 = fmaxf(fmaxf(c3, c4), c5);
  float t2 = fmaxf(fmaxf(t0, c6), c7);
  float m  = fmaxf(t2, t1);
  float M  = xhalf_max(m);          // full 16-way max for tag n, all lanes
  float Mr = rotr<8>(M);            // M[(n-8)&15] = M[n^8]
  float base = hi ? Mr : M;
  return base + fb;                 // new fvh = nf[nid]
}

// ---------------------------------------------------------------------------
// K1: value-only exact Viterbi forward chain. ONE wave, lean critical path.
// No FV streaming: stores a 64B checkpoint (fv entering step t) every CSZ
// steps; k_fv regenerates the full FV array in parallel, bit-exact.
// ---------------------------------------------------------------------------
__global__ __launch_bounds__(64)
void k_chain(const float* __restrict__ feats, const float* __restrict__ trans,
             float* __restrict__ CKPT, int* __restrict__ last_tag, int T) {
  const int l = threadIdx.x;
  const int n = l & 15;
  const bool hi = (l & 32) != 0;
  const int nid = n ^ (hi ? 8 : 0);

  float trr[8];
  #pragma unroll
  for (int i = 0; i < 8; ++i) trr[i] = trans[n * 16 + ((nid - i) & 15)];

  float fvh = 0.0f; // fv[nid] = 0 initially

  float fbuf[PF];
  #pragma unroll
  for (int i = 0; i < PF; ++i) {
    int idx = i < T ? i : (T - 1);
    fbuf[i] = feats[(size_t)idx * 16 + nid];
  }

  int t = 0;
  const int Tm = T - (T % PF);
  for (; t < Tm; t += PF) {
    if ((t & (CSZ - 1)) == 0) CKPT[(size_t)(t >> CSB) * 16 + nid] = fvh;
    #pragma unroll
    for (int u = 0; u < PF; ++u) {
      const int tt = t + u;
      fvh = step8(fvh, trr, hi, fbuf[u]);
      int pfi = tt + PF; if (pfi > T - 1) pfi = T - 1;
      fbuf[u] = feats[(size_t)pfi * 16 + nid];
    }
  }
  for (; t < T; ++t) { // tail
    if ((t & (CSZ - 1)) == 0) CKPT[(size_t)(t >> CSB) * 16 + nid] = fvh;
    fvh = step8(fvh, trr, hi, feats[(size_t)t * 16 + nid]);
  }

  // last_tag = argmax of final fv (first-index tie-break, ascending p).
  // Lower lanes (l<16) hold unshifted fv[n].
  float bv = __shfl(fvh, 0, 64); int bi = 0;
  #pragma unroll
  for (int p = 1; p < 16; ++p) {
    float ov = __shfl(fvh, p, 64);
    if (ov > bv) { bv = ov; bi = p; }
  }
  if (l == 0) *last_tag = bi;
}

// ---------------------------------------------------------------------------
// K1b: parallel FV regeneration. One wave per CSZ-step chunk; replays the
// identical fp32 recurrence from the chunk's checkpoint -> bit-exact FV.
// Throughput-bound (thousands of independent waves).
// ---------------------------------------------------------------------------
__global__ __launch_bounds__(256)
void k_fv(const float* __restrict__ CKPT, const float* __restrict__ trans,
          const float* __restrict__ feats, float* __restrict__ FV, int T, int NC) {
  const int tid = threadIdx.x;
  const int wid = blockIdx.x * 4 + (tid >> 6);
  const int l = tid & 63;
  const int n = l & 15;
  if (wid >= NC) return;

  float trr[16];
  #pragma unroll
  for (int k = 0; k < 16; ++k) trr[k] = trans[n * 16 + ((n - k) & 15)];

  float fv = CKPT[(size_t)wid * 16 + n];
  const int a = wid * CSZ;
  int b = a + CSZ; if (b > T) b = T;
  for (int t = a; t < b; ++t) {
    FV[(size_t)t * 16 + n] = fv;            // FV[t] = fv entering step t
    fv = vstep(fv, trr) + feats[(size_t)t * 16 + n];
  }
}

// ---------------------------------------------------------------------------
// K2: parallel backpointer recompute. Thread per t.
// bp[t][n] = argmax_p fl(FV[t][p] + tr[n][p]), strict-> scan (first-max),
// bit-identical to the reference's jnp.argmax(scores, axis=1).
// ---------------------------------------------------------------------------
__global__ __launch_bounds__(256)
void k_bp(const float* __restrict__ FV, const float* __restrict__ trans,
          uint4* __restrict__ bp, int T) {
  __shared__ float str[256];
  const int tid = threadIdx.x;
  str[tid] = trans[tid];
  __syncthreads();
  const int t = blockIdx.x * blockDim.x + tid;
  if (t >= T) return;
  const float4* fr = (const float4*)(FV + (size_t)t * 16);
  float4 q0 = fr[0], q1 = fr[1], q2 = fr[2], q3 = fr[3];
  float fv[16] = {q0.x, q0.y, q0.z, q0.w, q1.x, q1.y, q1.z, q1.w,
                  q2.x, q2.y, q2.z, q2.w, q3.x, q3.y, q3.z, q3.w};
  uint32_t w[4];
  #pragma unroll
  for (int g = 0; g < 4; ++g) {
    uint32_t word = 0;
    #pragma unroll
    for (int s = 0; s < 4; ++s) {
      const int nn = 4 * g + s;
      float best = fv[0] + str[nn * 16 + 0];
      int bi = 0;
      #pragma unroll
      for (int p = 1; p < 16; ++p) {
        float v = fv[p] + str[nn * 16 + p];
        if (v > best) { best = v; bi = p; }
      }
      word |= (uint32_t)bi << (8 * s);
    }
    w[g] = word;
  }
  bp[t] = make_uint4(w[0], w[1], w[2], w[3]);
}

// ---------------------------------------------------------------------------
// K3: per-chunk 16-hypothesis backtrack (exact integer pointer chase).
// ---------------------------------------------------------------------------
__global__ __launch_bounds__(64)
void k_chase(const unsigned char* __restrict__ bp, unsigned char* __restrict__ st,
             unsigned char* __restrict__ maps, int T, int C) {
  const int tid = threadIdx.x;
  const int chunk = blockIdx.x * 4 + (tid >> 4);
  const int h = tid & 15;
  if (chunk >= C) return;
  const int a = chunk * L4;
  int b = a + L4; if (b > T) b = T;
  int cur = h;
  for (int t = b - 1; t >= a; --t) {
    cur = bp[(size_t)t * 16 + cur];
    st[(size_t)t * 16 + h] = (unsigned char)cur;
  }
  maps[chunk * 16 + h] = (unsigned char)cur;
}

// ---------------------------------------------------------------------------
// K4: compose GRP consecutive chunk maps into one super-map per group.
// ---------------------------------------------------------------------------
__global__ __launch_bounds__(64)
void k_group(const unsigned char* __restrict__ maps, unsigned char* __restrict__ sup,
             int C, int NG) {
  const int g = blockIdx.x;
  const int e = threadIdx.x;
  if (g >= NG || e >= 16) return;
  int hi = g * GRP + GRP - 1; if (hi > C - 1) hi = C - 1;
  int cur = e;
  for (int c = hi; c >= g * GRP; --c) cur = maps[c * 16 + cur];
  sup[g * 16 + e] = (unsigned char)cur;
}

// ---------------------------------------------------------------------------
// K5: resolve true tag at every chunk's end boundary.
// ---------------------------------------------------------------------------
__global__ __launch_bounds__(128)
void k_resolve(const unsigned char* __restrict__ maps, const unsigned char* __restrict__ sup,
               const int* __restrict__ last_tag, unsigned char* __restrict__ s_arr,
               int C, int NG) {
  __shared__ unsigned char Sg[4096];
  const int tid = threadIdx.x;
  if (tid == 0) {
    int cur = *last_tag;
    for (int g = NG - 1; g >= 0; --g) {
      Sg[g] = (unsigned char)cur;
      cur = sup[g * 16 + cur];
    }
  }
  __syncthreads();
  for (int g = tid; g < NG; g += blockDim.x) {
    int cur = Sg[g];
    int hi = g * GRP + GRP - 1; if (hi > C - 1) hi = C - 1;
    for (int c = hi; c >= g * GRP; --c) {
      s_arr[c] = (unsigned char)cur;
      cur = maps[c * 16 + cur];
    }
  }
}

// ---------------------------------------------------------------------------
// K6: emit out[t] = st[t*16 + s_arr[t / L4]] as int32.
// ---------------------------------------------------------------------------
__global__ void k_emit(const unsigned char* __restrict__ st,
                       const unsigned char* __restrict__ s_arr,
                       int* __restrict__ out, int T) {
  int t = blockIdx.x * blockDim.x + threadIdx.x;
  if (t < T) out[t] = (int)st[(size_t)t * 16 + s_arr[t / L4]];
}

extern "C" void kernel_launch(void* const* d_in, const int* in_sizes, int n_in,
                              void* d_out, int out_size, void* d_ws, size_t ws_size,
                              hipStream_t stream) {
  const float* feats = (const float*)d_in[0];   // [1, T, 16] fp32
  const float* trans = (const float*)d_in[1];   // [16, 16]  fp32
  int* out = (int*)d_out;                       // [T] int32

  const int T  = in_sizes[0] / 16;
  const int C  = (T + L4 - 1) / L4;
  const int NG = (C + GRP - 1) / GRP;
  const int NC = (T + CSZ - 1) / CSZ;

  char* ws = (char*)d_ws;
  float* FV           = (float*)ws;                           // (T+1)*16 floats
  float* CKPT         = FV + (size_t)(T + 1) * 16;            // NC*16 floats
  unsigned char* bp   = (unsigned char*)(CKPT + (size_t)NC * 16); // T*16 B, 16B-aligned
  unsigned char* st   = bp + (size_t)T * 16;                  // T*16 B
  unsigned char* maps = st + (size_t)T * 16;                  // C*16
  unsigned char* sup  = maps + (size_t)C * 16;                // NG*16
  unsigned char* sarr = sup + (size_t)NG * 16;                // C
  int* last_tag = (int*)(((uintptr_t)(sarr + C) + 15) & ~(uintptr_t)15);
  size_t need = (size_t)((char*)(last_tag + 1) - ws);
  if (ws_size < need) return;  // insufficient scratch -> fail visibly

  k_chain<<<1, 64, 0, stream>>>(feats, trans, CKPT, last_tag, T);
  k_fv<<<(NC + 3) / 4, 256, 0, stream>>>(CKPT, trans, feats, FV, T, NC);
  k_bp<<<(T + 255) / 256, 256, 0, stream>>>(FV, trans, (uint4*)bp, T);
  k_chase<<<(C + 3) / 4, 64, 0, stream>>>(bp, st, maps, T, C);
  k_group<<<NG, 64, 0, stream>>>(maps, sup, C, NG);
  k_resolve<<<1, 128, 0, stream>>>(maps, sup, last_tag, sarr, C, NG);
  const int thr = 256;
  k_emit<<<(T + thr - 1) / thr, thr, 0, stream>>>(st, sarr, out, T);
}

// Round 4
// 62601.868 us; speedup vs baseline: 1.4649x; 1.0759x over previous
//
#include <hip/hip_runtime.h>
#include <stdint.h>

#define L4   250   // chase chunk length
#define GRP  50    // chunks per map-composition group
#define PF   32    // feat prefetch depth in k_chain
#define CSZ  256   // checkpoint interval (power of 2)
#define CSB  8     // log2(CSZ)

// DPP row_ror:K — dst lane i reads src lane (i-K)&15 within its row of 16.
// Direction HW-validated bit-exact (absmax 0) in prior rounds.
template<int K>
__device__ __forceinline__ float rotr(float x) {
  return __int_as_float(__builtin_amdgcn_mov_dpp(__float_as_int(x), 0x120 + K, 0xF, 0xF, false));
}

// Cross-half (lane l <-> l^32) max, VALU-speed on gfx950 via permlane32_swap.
// Feeding (m,m) and maxing both outputs yields max(m[l], m[l^32]) regardless
// of which output carries which half. HW-validated (absmax 0, round 3).
__device__ __forceinline__ float xhalf_max(float m) {
#if __has_builtin(__builtin_amdgcn_permlane32_swap)
  typedef int v2i __attribute__((ext_vector_type(2)));
  v2i r = __builtin_amdgcn_permlane32_swap(__float_as_int(m), __float_as_int(m), false, false);
  return fmaxf(__int_as_float(r[0]), __int_as_float(r[1]));
#else
  return fmaxf(m, __shfl_xor(m, 32, 64));
#endif
}

// Masked-row rotate: rows 0,1 (lanes 0-31) keep M; rows 2,3 (lanes 32-63)
// get M[(n-8)&15] = M[n^8] via row_ror:8. One v_mov_b32_dpp with
// row_mask=0xC replaces rotr<8> + cndmask (masked-out rows retain old).
__device__ __forceinline__ float selrot8(float M, bool hi) {
#if __has_builtin(__builtin_amdgcn_update_dpp)
  int Mi = __float_as_int(M);
  return __int_as_float(__builtin_amdgcn_update_dpp(Mi, Mi, 0x128, 0xC, 0xF, false));
#else
  float Mr = rotr<8>(M);
  return hi ? Mr : M;
#endif
}

// Full 16-candidate exact step (used by throughput kernel k_fv).
// Lane layout: n = lane&15, lane holds fv[n]; trr[k] = tr[n][(n-k)&15].
// fp32 max over 16 finite values is order-independent -> bit-identical to
// the reference's jnp.max regardless of tree shape.
__device__ __forceinline__ float vstep(float fv, const float* __restrict__ trr) {
  float c0  = fv           + trr[0];
  float c1  = rotr<1 >(fv) + trr[1];
  float c2  = rotr<2 >(fv) + trr[2];
  float c3  = rotr<3 >(fv) + trr[3];
  float c4  = rotr<4 >(fv) + trr[4];
  float c5  = rotr<5 >(fv) + trr[5];
  float c6  = rotr<6 >(fv) + trr[6];
  float c7  = rotr<7 >(fv) + trr[7];
  float c8  = rotr<8 >(fv) + trr[8];
  float c9  = rotr<9 >(fv) + trr[9];
  float c10 = rotr<10>(fv) + trr[10];
  float c11 = rotr<11>(fv) + trr[11];
  float c12 = rotr<12>(fv) + trr[12];
  float c13 = rotr<13>(fv) + trr[13];
  float c14 = rotr<14>(fv) + trr[14];
  float c15 = rotr<15>(fv) + trr[15];
  float t0 = fmaxf(fmaxf(c0,  c1),  c2);
  float t1 = fmaxf(fmaxf(c3,  c4),  c5);
  float t2 = fmaxf(fmaxf(c6,  c7),  c8);
  float t3 = fmaxf(fmaxf(c9,  c10), c11);
  float t4 = fmaxf(fmaxf(c12, c13), c14);
  float u0 = fmaxf(fmaxf(t0, t1), t2);
  float u1 = fmaxf(fmaxf(t3, t4), c15);
  return fmaxf(u0, u1);
}

// Split 8-candidate exact step (serial chain). Invariant: lane (h,n) holds
// fvh = fv[nid], nid = n ^ (8h) = (n+8h) mod 16. Uniform rotr<i>(fvh) at lane
// (h,n) gives fv[(nid-i)&15]; trr[i] = tr[n][(nid-i)&15]; union over h,i =
// all 16 p, each exactly once. Cross-half merge gives the full max M for tag
// n in all lanes (bit-exact: float max is order-independent; candidate adds
// identical to reference). Next-state: lane holds nf[nid]; selrot8 supplies
// M[n^8] to the upper half in one masked DPP.
__device__ __forceinline__ float step8(float fvh, const float* __restrict__ trr,
                                       bool hi, float fb) {
  float c0 = fvh          + trr[0];
  float c1 = rotr<1>(fvh) + trr[1];
  float c2 = rotr<2>(fvh) + trr[2];
  float c3 = rotr<3>(fvh) + trr[3];
  float c4 = rotr<4>(fvh) + trr[4];
  float c5 = rotr<5>(fvh) + trr[5];
  float c6 = rotr<6>(fvh) + trr[6];
  float c7 = rotr<7>(fvh) + trr[7];
  float a = fmaxf(fmaxf(c0, c1), c2);   // v_max3
  float b = fmaxf(fmaxf(c3, c4), c5);   // v_max3
  float w = fmaxf(c6, c7);
  float m = fmaxf(fmaxf(a, b), w);      // v_max3 (depth 2 after adds)
  float M = xhalf_max(m);               // full 16-way max for tag n, all lanes
  float base = selrot8(M, hi);          // lo: M[n], hi: M[n^8]
  return base + fb;                     // new fvh = nf[nid]
}

// ---------------------------------------------------------------------------
// K1: value-only exact Viterbi forward chain. ONE wave, lean critical path.
// Clamp-free prefetch: main loop runs to Tm <= T-PF so prefetch index never
// needs clamping; uniform block pointer + compile-time offsets -> one
// global_load_dword with imm offset per step, zero per-step VALU addressing.
// Stores a 64B checkpoint every CSZ steps; k_fv regenerates FV in parallel.
// ---------------------------------------------------------------------------
__global__ __launch_bounds__(64)
void k_chain(const float* __restrict__ feats, const float* __restrict__ trans,
             float* __restrict__ CKPT, int* __restrict__ last_tag, int T) {
  const int l = threadIdx.x;
  const int n = l & 15;
  const bool hi = (l & 32) != 0;
  const int nid = n ^ (hi ? 8 : 0);

  float trr[8];
  #pragma unroll
  for (int i = 0; i < 8; ++i) trr[i] = trans[n * 16 + ((nid - i) & 15)];

  float fvh = 0.0f; // fv[nid] = 0 initially

  float fbuf[PF];
  #pragma unroll
  for (int i = 0; i < PF; ++i) {
    int idx = i < T ? i : (T - 1);
    fbuf[i] = feats[(size_t)idx * 16 + nid];
  }

  int t = 0;
  const int Tm = (T >= 2 * PF) ? ((T - PF) & ~(PF - 1)) : 0;
  for (; t < Tm; t += PF) {
    if ((t & (CSZ - 1)) == 0) CKPT[(size_t)(t >> CSB) * 16 + nid] = fvh;
    const float* __restrict__ pf_ptr = feats + (size_t)(t + PF) * 16; // uniform
    #pragma unroll
    for (int u = 0; u < PF; ++u) {
      fvh = step8(fvh, trr, hi, fbuf[u]);
      fbuf[u] = pf_ptr[u * 16 + nid];   // imm-offset load, never OOB (t+u+PF <= T-1)
    }
  }
  for (; t < T; ++t) { // tail (< 2*PF steps): direct loads, cache-hot lines
    if ((t & (CSZ - 1)) == 0) CKPT[(size_t)(t >> CSB) * 16 + nid] = fvh;
    fvh = step8(fvh, trr, hi, feats[(size_t)t * 16 + nid]);
  }

  // last_tag = argmax of final fv (first-index tie-break, ascending p).
  // Lower lanes (l<16) hold unshifted fv[n].
  float bv = __shfl(fvh, 0, 64); int bi = 0;
  #pragma unroll
  for (int p = 1; p < 16; ++p) {
    float ov = __shfl(fvh, p, 64);
    if (ov > bv) { bv = ov; bi = p; }
  }
  if (l == 0) *last_tag = bi;
}

// ---------------------------------------------------------------------------
// K1b: parallel FV regeneration. One wave per CSZ-step chunk; replays the
// identical fp32 recurrence from the chunk's checkpoint -> bit-exact FV.
// Throughput-bound (thousands of independent waves).
// ---------------------------------------------------------------------------
__global__ __launch_bounds__(256)
void k_fv(const float* __restrict__ CKPT, const float* __restrict__ trans,
          const float* __restrict__ feats, float* __restrict__ FV, int T, int NC) {
  const int tid = threadIdx.x;
  const int wid = blockIdx.x * 4 + (tid >> 6);
  const int l = tid & 63;
  const int n = l & 15;
  if (wid >= NC) return;

  float trr[16];
  #pragma unroll
  for (int k = 0; k < 16; ++k) trr[k] = trans[n * 16 + ((n - k) & 15)];

  float fv = CKPT[(size_t)wid * 16 + n];
  const int a = wid * CSZ;
  int b = a + CSZ; if (b > T) b = T;
  for (int t = a; t < b; ++t) {
    FV[(size_t)t * 16 + n] = fv;            // FV[t] = fv entering step t
    fv = vstep(fv, trr) + feats[(size_t)t * 16 + n];
  }
}

// ---------------------------------------------------------------------------
// K2: parallel backpointer recompute. Thread per t.
// bp[t][n] = argmax_p fl(FV[t][p] + tr[n][p]), strict-> scan (first-max),
// bit-identical to the reference's jnp.argmax(scores, axis=1).
// ---------------------------------------------------------------------------
__global__ __launch_bounds__(256)
void k_bp(const float* __restrict__ FV, const float* __restrict__ trans,
          uint4* __restrict__ bp, int T) {
  __shared__ float str[256];
  const int tid = threadIdx.x;
  str[tid] = trans[tid];
  __syncthreads();
  const int t = blockIdx.x * blockDim.x + tid;
  if (t >= T) return;
  const float4* fr = (const float4*)(FV + (size_t)t * 16);
  float4 q0 = fr[0], q1 = fr[1], q2 = fr[2], q3 = fr[3];
  float fv[16] = {q0.x, q0.y, q0.z, q0.w, q1.x, q1.y, q1.z, q1.w,
                  q2.x, q2.y, q2.z, q2.w, q3.x, q3.y, q3.z, q3.w};
  uint32_t w[4];
  #pragma unroll
  for (int g = 0; g < 4; ++g) {
    uint32_t word = 0;
    #pragma unroll
    for (int s = 0; s < 4; ++s) {
      const int nn = 4 * g + s;
      float best = fv[0] + str[nn * 16 + 0];
      int bi = 0;
      #pragma unroll
      for (int p = 1; p < 16; ++p) {
        float v = fv[p] + str[nn * 16 + p];
        if (v > best) { best = v; bi = p; }
      }
      word |= (uint32_t)bi << (8 * s);
    }
    w[g] = word;
  }
  bp[t] = make_uint4(w[0], w[1], w[2], w[3]);
}

// ---------------------------------------------------------------------------
// K3: per-chunk 16-hypothesis backtrack (exact integer pointer chase).
// ---------------------------------------------------------------------------
__global__ __launch_bounds__(64)
void k_chase(const unsigned char* __restrict__ bp, unsigned char* __restrict__ st,
             unsigned char* __restrict__ maps, int T, int C) {
  const int tid = threadIdx.x;
  const int chunk = blockIdx.x * 4 + (tid >> 4);
  const int h = tid & 15;
  if (chunk >= C) return;
  const int a = chunk * L4;
  int b = a + L4; if (b > T) b = T;
  int cur = h;
  for (int t = b - 1; t >= a; --t) {
    cur = bp[(size_t)t * 16 + cur];
    st[(size_t)t * 16 + h] = (unsigned char)cur;
  }
  maps[chunk * 16 + h] = (unsigned char)cur;
}

// ---------------------------------------------------------------------------
// K4: compose GRP consecutive chunk maps into one super-map per group.
// ---------------------------------------------------------------------------
__global__ __launch_bounds__(64)
void k_group(const unsigned char* __restrict__ maps, unsigned char* __restrict__ sup,
             int C, int NG) {
  const int g = blockIdx.x;
  const int e = threadIdx.x;
  if (g >= NG || e >= 16) return;
  int hi = g * GRP + GRP - 1; if (hi > C - 1) hi = C - 1;
  int cur = e;
  for (int c = hi; c >= g * GRP; --c) cur = maps[c * 16 + cur];
  sup[g * 16 + e] = (unsigned char)cur;
}

// ---------------------------------------------------------------------------
// K5: resolve true tag at every chunk's end boundary.
// ---------------------------------------------------------------------------
__global__ __launch_bounds__(128)
void k_resolve(const unsigned char* __restrict__ maps, const unsigned char* __restrict__ sup,
               const int* __restrict__ last_tag, unsigned char* __restrict__ s_arr,
               int C, int NG) {
  __shared__ unsigned char Sg[4096];
  const int tid = threadIdx.x;
  if (tid == 0) {
    int cur = *last_tag;
    for (int g = NG - 1; g >= 0; --g) {
      Sg[g] = (unsigned char)cur;
      cur = sup[g * 16 + cur];
    }
  }
  __syncthreads();
  for (int g = tid; g < NG; g += blockDim.x) {
    int cur = Sg[g];
    int hi = g * GRP + GRP - 1; if (hi > C - 1) hi = C - 1;
    for (int c = hi; c >= g * GRP; --c) {
      s_arr[c] = (unsigned char)cur;
      cur = maps[c * 16 + cur];
    }
  }
}

// ---------------------------------------------------------------------------
// K6: emit out[t] = st[t*16 + s_arr[t / L4]] as int32.
// ---------------------------------------------------------------------------
__global__ void k_emit(const unsigned char* __restrict__ st,
                       const unsigned char* __restrict__ s_arr,
                       int* __restrict__ out, int T) {
  int t = blockIdx.x * blockDim.x + threadIdx.x;
  if (t < T) out[t] = (int)st[(size_t)t * 16 + s_arr[t / L4]];
}

extern "C" void kernel_launch(void* const* d_in, const int* in_sizes, int n_in,
                              void* d_out, int out_size, void* d_ws, size_t ws_size,
                              hipStream_t stream) {
  const float* feats = (const float*)d_in[0];   // [1, T, 16] fp32
  const float* trans = (const float*)d_in[1];   // [16, 16]  fp32
  int* out = (int*)d_out;                       // [T] int32

  const int T  = in_sizes[0] / 16;
  const int C  = (T + L4 - 1) / L4;
  const int NG = (C + GRP - 1) / GRP;
  const int NC = (T + CSZ - 1) / CSZ;

  char* ws = (char*)d_ws;
  float* FV           = (float*)ws;                           // (T+1)*16 floats
  float* CKPT         = FV + (size_t)(T + 1) * 16;            // NC*16 floats
  unsigned char* bp   = (unsigned char*)(CKPT + (size_t)NC * 16); // T*16 B, 16B-aligned
  unsigned char* st   = bp + (size_t)T * 16;                  // T*16 B
  unsigned char* maps = st + (size_t)T * 16;                  // C*16
  unsigned char* sup  = maps + (size_t)C * 16;                // NG*16
  unsigned char* sarr = sup + (size_t)NG * 16;                // C
  int* last_tag = (int*)(((uintptr_t)(sarr + C) + 15) & ~(uintptr_t)15);
  size_t need = (size_t)((char*)(last_tag + 1) - ws);
  if (ws_size < need) return;  // insufficient scratch -> fail visibly

  k_chain<<<1, 64, 0, stream>>>(feats, trans, CKPT, last_tag, T);
  k_fv<<<(NC + 3) / 4, 256, 0, stream>>>(CKPT, trans, feats, FV, T, NC);
  k_bp<<<(T + 255) / 256, 256, 0, stream>>>(FV, trans, (uint4*)bp, T);
  k_chase<<<(C + 3) / 4, 64, 0, stream>>>(bp, st, maps, T, C);
  k_group<<<NG, 64, 0, stream>>>(maps, sup, C, NG);
  k_resolve<<<1, 128, 0, stream>>>(maps, sup, last_tag, sarr, C, NG);
  const int thr = 256;
  k_emit<<<(T + thr - 1) / thr, thr, 0, stream>>>(st, sarr, out, T);
}